// Round 7
// baseline (930.582 us; speedup 1.0000x reference)
//
#include <hip/hip_runtime.h>

// CRITICAL: bit-exact replication of the numpy fp32 oracle requires NO FMA
// contraction (hipcc default -ffp-contract=fast-honor-pragmas would fuse).
#pragma clang fp contract(off)

#define D4    83521      // 17^4 entries per LUT (per channel)
#define HW    262144     // 512*512
#define NPIX  2097152    // 8*512*512
#define QREC  73984      // 17*17*16*16 quad records per LUT

// ---------- quad packing: one 64B record = 2x2 (i2,i3) corner block ----------
// Record r = ((i0*17 + i1)*16 + i2)*16 + i3, i2,i3 in [0,16).
// Slot g (g=0..3) holds channels of corner (i2 + (g&1), i3 + (g>>1)) —
// exactly the order the accumulation consumes groups.
__global__ __launch_bounds__(256) void pack_quad(const float* __restrict__ src,
                                                 int n_ch,
                                                 float4* __restrict__ dst) {
    int e = blockIdx.x * 256 + threadIdx.x;
    if (e >= QREC) return;
    int i3 = e & 15;
    int i2 = (e >> 4) & 15;
    int t  = e >> 8;              // i0*17 + i1, in [0,289)
    int i0 = t / 17;
    int i1 = t - i0 * 17;
    int base = i0 * 4913 + i1 * 289 + i2 * 17 + i3;
    float4* rec = dst + (size_t)e * 4;
#pragma unroll
    for (int g = 0; g < 4; ++g) {
        int o = base + (g & 1) * 17 + (g >> 1);
        float4 v;
        v.x = src[o];
        v.y = src[D4 + o];
        v.z = src[2 * D4 + o];
        v.w = (n_ch == 4) ? src[3 * D4 + o] : 0.f;
        rec[g] = v;
    }
}

// Fused 6-stage chain using quad records: 4 cacheline-misses per pixel-stage
// (records (i0+b0, i1+b1)); the 12 remaining 16B loads are same-line L1
// hits/merges. Arithmetic is instruction-identical to the verified round-6
// kernel: fp32, no contraction, weights ((w0*w1)*w2)*w3, corners 0..15
// strictly sequential (bit k of corner selects dim k).
__global__ __launch_bounds__(256) void fused_quad(const float* __restrict__ vi,
                                                  const float* __restrict__ ir,
                                                  const float4* __restrict__ luts,
                                                  float* __restrict__ out) {
#pragma clang fp contract(off)
    int p = blockIdx.x * 256 + threadIdx.x;
    if (p >= NPIX) return;
    int b  = p >> 18;             // HW = 2^18
    int hw = p & (HW - 1);
    int vbase = (b * 3) << 18;

    float x0 = vi[vbase + hw];
    float x1 = vi[vbase + HW + hw];
    float x2 = vi[vbase + 2 * HW + hw];
    float x3 = ir[p];

    for (int s = 0; s < 6; ++s) {
        const float4* __restrict__ lut = luts + (size_t)s * QREC * 4;
        x0 = fminf(fmaxf(x0, 0.f), 1.f);
        x1 = fminf(fmaxf(x1, 0.f), 1.f);
        x2 = fminf(fmaxf(x2, 0.f), 1.f);
        x3 = fminf(fmaxf(x3, 0.f), 1.f);

        float xs0 = x0 * 16.f;
        float xs1 = x1 * 16.f;
        float xs2 = x2 * 16.f;
        float xs3 = x3 * 16.f;
        int i0 = (int)xs0; i0 = i0 > 15 ? 15 : i0;
        int i1 = (int)xs1; i1 = i1 > 15 ? 15 : i1;
        int i2 = (int)xs2; i2 = i2 > 15 ? 15 : i2;
        int i3 = (int)xs3; i3 = i3 > 15 ? 15 : i3;
        float f0 = xs0 - (float)i0;   // mul-then-sub, contraction OFF
        float f1 = xs1 - (float)i1;
        float f2 = xs2 - (float)i2;
        float f3 = xs3 - (float)i3;
        float g0 = 1.f - f0;
        float g1 = 1.f - f1;
        float g2 = 1.f - f2;
        float g3 = 1.f - f3;

        // w01[b1*2+b0] = (b0?f0:g0)*(b1?f1:g1)
        float w01[4] = { g0 * g1, f0 * g1, g0 * f1, f0 * f1 };

        // 4 records: (i0+b0, i1+b1); strides: i0->4352 records, i1->256.
        int r00 = ((i0 * 17 + i1) * 16 + i2) * 16 + i3;
        const float4* q00 = lut + (size_t)r00 * 4;
        const float4* q10 = q00 + (size_t)4352 * 4;
        const float4* q01 = q00 + (size_t)256 * 4;
        const float4* q11 = q00 + (size_t)4608 * 4;

        float a0 = 0.f, a1 = 0.f, a2 = 0.f, a3 = 0.f;
        // group g = b3*2 + b2; corners g*4 + (b1*2+b0), sequential 0..15.
#pragma unroll
        for (int g = 0; g < 4; ++g) {
            float w2b = (g & 1) ? f2 : g2;
            float w3b = (g >> 1) ? f3 : g3;
            float4 v0 = q00[g];            // (b0,b1)=(0,0)
            float4 v1 = q10[g];            // (1,0)
            float4 v2 = q01[g];            // (0,1)
            float4 v3 = q11[g];            // (1,1)
            float w;
            w = (w01[0] * w2b) * w3b;
            if (g == 0) {
                a0 = v0.x * w; a1 = v0.y * w; a2 = v0.z * w; a3 = v0.w * w;
            } else {
                a0 = a0 + v0.x * w; a1 = a1 + v0.y * w;
                a2 = a2 + v0.z * w; a3 = a3 + v0.w * w;
            }
            w = (w01[1] * w2b) * w3b;
            a0 = a0 + v1.x * w; a1 = a1 + v1.y * w;
            a2 = a2 + v1.z * w; a3 = a3 + v1.w * w;
            w = (w01[2] * w2b) * w3b;
            a0 = a0 + v2.x * w; a1 = a1 + v2.y * w;
            a2 = a2 + v2.z * w; a3 = a3 + v2.w * w;
            w = (w01[3] * w2b) * w3b;
            a0 = a0 + v3.x * w; a1 = a1 + v3.y * w;
            a2 = a2 + v3.z * w; a3 = a3 + v3.w * w;
        }
        x0 = a0; x1 = a1; x2 = a2; x3 = a3;
    }

    out[vbase + hw]          = x0;
    out[vbase + HW + hw]     = x1;
    out[vbase + 2 * HW + hw] = x2;
}

// ---------- middle tier: round-6 linear float4 packing (known-passing) ------
__global__ __launch_bounds__(256) void pack_kernel(const float* __restrict__ src,
                                                   int n_ch,
                                                   float4* __restrict__ dst) {
    int e = blockIdx.x * 256 + threadIdx.x;
    if (e >= D4) return;
    float4 v;
    v.x = src[e];
    v.y = src[D4 + e];
    v.z = src[2 * D4 + e];
    v.w = (n_ch == 4) ? src[3 * D4 + e] : 0.f;
    dst[e] = v;
}

__global__ __launch_bounds__(256) void fused_kernel(const float* __restrict__ vi,
                                                    const float* __restrict__ ir,
                                                    const float4* __restrict__ luts,
                                                    float* __restrict__ out) {
#pragma clang fp contract(off)
    int p = blockIdx.x * 256 + threadIdx.x;
    if (p >= NPIX) return;
    int b  = p >> 18;
    int hw = p & (HW - 1);
    int vbase = (b * 3) << 18;

    float x0 = vi[vbase + hw];
    float x1 = vi[vbase + HW + hw];
    float x2 = vi[vbase + 2 * HW + hw];
    float x3 = ir[p];

    for (int s = 0; s < 6; ++s) {
        const float4* __restrict__ lut = luts + (size_t)s * D4;
        x0 = fminf(fmaxf(x0, 0.f), 1.f);
        x1 = fminf(fmaxf(x1, 0.f), 1.f);
        x2 = fminf(fmaxf(x2, 0.f), 1.f);
        x3 = fminf(fmaxf(x3, 0.f), 1.f);

        float xs0 = x0 * 16.f;
        float xs1 = x1 * 16.f;
        float xs2 = x2 * 16.f;
        float xs3 = x3 * 16.f;
        int i0 = (int)xs0; i0 = i0 > 15 ? 15 : i0;
        int i1 = (int)xs1; i1 = i1 > 15 ? 15 : i1;
        int i2 = (int)xs2; i2 = i2 > 15 ? 15 : i2;
        int i3 = (int)xs3; i3 = i3 > 15 ? 15 : i3;
        float f0 = xs0 - (float)i0;
        float f1 = xs1 - (float)i1;
        float f2 = xs2 - (float)i2;
        float f3 = xs3 - (float)i3;
        float g0 = 1.f - f0;
        float g1 = 1.f - f1;
        float g2 = 1.f - f2;
        float g3 = 1.f - f3;

        float w01[4] = { g0 * g1, f0 * g1, g0 * f1, f0 * f1 };
        int off = i0 * 4913 + i1 * 289 + i2 * 17 + i3;

        float a0 = 0.f, a1 = 0.f, a2 = 0.f, a3 = 0.f;
#pragma unroll
        for (int hi = 0; hi < 2; ++hi) {
            float w3 = hi ? f3 : g3;
#pragma unroll
            for (int c = 0; c < 8; ++c) {
                int d = (c & 1) * 4913 + ((c >> 1) & 1) * 289 + (c >> 2) * 17 + hi;
                float4 v = lut[off + d];
                float w012 = w01[c & 3] * ((c >> 2) ? f2 : g2);
                float w    = w012 * w3;
                if (hi == 0 && c == 0) {
                    a0 = v.x * w; a1 = v.y * w; a2 = v.z * w; a3 = v.w * w;
                } else {
                    a0 = a0 + v.x * w; a1 = a1 + v.y * w;
                    a2 = a2 + v.z * w; a3 = a3 + v.w * w;
                }
            }
        }
        x0 = a0; x1 = a1; x2 = a2; x3 = a3;
    }

    out[vbase + hw]          = x0;
    out[vbase + HW + hw]     = x1;
    out[vbase + 2 * HW + hw] = x2;
}

// ---------- raw fallback (no workspace) -------------------------------------
__global__ __launch_bounds__(256) void fused_fallback(const float* __restrict__ vi,
                                                      const float* __restrict__ ir,
                                                      const float* __restrict__ l8,
                                                      const float* __restrict__ l00,
                                                      const float* __restrict__ l01,
                                                      const float* __restrict__ l02,
                                                      const float* __restrict__ l03,
                                                      const float* __restrict__ lpgf,
                                                      float* __restrict__ out) {
#pragma clang fp contract(off)
    int p = blockIdx.x * 256 + threadIdx.x;
    if (p >= NPIX) return;
    int b  = p >> 18;
    int hw = p & (HW - 1);
    int vbase = (b * 3) << 18;

    const float* ptrs[6] = { l8, l00, l01, l02, l03, lpgf };

    float x0 = vi[vbase + hw];
    float x1 = vi[vbase + HW + hw];
    float x2 = vi[vbase + 2 * HW + hw];
    float x3 = ir[p];

    for (int s = 0; s < 6; ++s) {
        const float* __restrict__ L = ptrs[s];
        int n_ch = (s == 5) ? 3 : 4;
        x0 = fminf(fmaxf(x0, 0.f), 1.f);
        x1 = fminf(fmaxf(x1, 0.f), 1.f);
        x2 = fminf(fmaxf(x2, 0.f), 1.f);
        x3 = fminf(fmaxf(x3, 0.f), 1.f);
        float xs0 = x0 * 16.f;
        float xs1 = x1 * 16.f;
        float xs2 = x2 * 16.f;
        float xs3 = x3 * 16.f;
        int i0 = (int)xs0; i0 = i0 > 15 ? 15 : i0;
        int i1 = (int)xs1; i1 = i1 > 15 ? 15 : i1;
        int i2 = (int)xs2; i2 = i2 > 15 ? 15 : i2;
        int i3 = (int)xs3; i3 = i3 > 15 ? 15 : i3;
        float f0 = xs0 - (float)i0;
        float f1 = xs1 - (float)i1;
        float f2 = xs2 - (float)i2;
        float f3 = xs3 - (float)i3;
        float g0 = 1.f - f0;
        float g1 = 1.f - f1;
        float g2 = 1.f - f2;
        float g3 = 1.f - f3;
        float w01[4] = { g0 * g1, f0 * g1, g0 * f1, f0 * f1 };
        int off = i0 * 4913 + i1 * 289 + i2 * 17 + i3;
        float a0 = 0.f, a1 = 0.f, a2 = 0.f, a3 = 0.f;
        for (int cr = 0; cr < 16; ++cr) {
            int hi = cr >> 3, c = cr & 7;
            int idx = off + (c & 1) * 4913 + ((c >> 1) & 1) * 289 + (c >> 2) * 17 + hi;
            float w012 = w01[c & 3] * ((c >> 2) ? f2 : g2);
            float w    = w012 * (hi ? f3 : g3);
            float v0 = L[idx];
            float v1 = L[D4 + idx];
            float v2 = L[2 * D4 + idx];
            float v3 = (n_ch == 4) ? L[3 * D4 + idx] : 0.f;
            if (cr == 0) {
                a0 = v0 * w; a1 = v1 * w; a2 = v2 * w; a3 = v3 * w;
            } else {
                a0 = a0 + v0 * w; a1 = a1 + v1 * w;
                a2 = a2 + v2 * w; a3 = a3 + v3 * w;
            }
        }
        x0 = a0; x1 = a1; x2 = a2; x3 = a3;
    }

    out[vbase + hw]          = x0;
    out[vbase + HW + hw]     = x1;
    out[vbase + 2 * HW + hw] = x2;
}

extern "C" void kernel_launch(void* const* d_in, const int* in_sizes, int n_in,
                              void* d_out, int out_size, void* d_ws, size_t ws_size,
                              hipStream_t stream) {
    const float* vi = (const float*)d_in[0];
    const float* ir = (const float*)d_in[1];
    const float* raw[6] = {
        (const float*)d_in[2], (const float*)d_in[3],
        (const float*)d_in[4], (const float*)d_in[5],
        (const float*)d_in[6], (const float*)d_in[7]
    };
    float* out = (float*)d_out;

    size_t need_quad = (size_t)6 * QREC * 64;        // ~28.4 MB
    size_t need_lin  = (size_t)6 * D4 * sizeof(float4);  // ~8.0 MB

    if (ws_size >= need_quad) {
        float4* packed = (float4*)d_ws;
        int pack_blocks = (QREC + 255) / 256;
        for (int s = 0; s < 6; ++s) {
            pack_quad<<<pack_blocks, 256, 0, stream>>>(raw[s], (s == 5) ? 3 : 4,
                                                       packed + (size_t)s * QREC * 4);
        }
        fused_quad<<<NPIX / 256, 256, 0, stream>>>(vi, ir, packed, out);
    } else if (ws_size >= need_lin) {
        float4* packed = (float4*)d_ws;
        int pack_blocks = (D4 + 255) / 256;
        for (int s = 0; s < 6; ++s) {
            pack_kernel<<<pack_blocks, 256, 0, stream>>>(raw[s], (s == 5) ? 3 : 4,
                                                         packed + (size_t)s * D4);
        }
        fused_kernel<<<NPIX / 256, 256, 0, stream>>>(vi, ir, packed, out);
    } else {
        fused_fallback<<<NPIX / 256, 256, 0, stream>>>(vi, ir, raw[0], raw[1], raw[2],
                                                       raw[3], raw[4], raw[5], out);
    }
}

// Round 8
// 857.195 us; speedup vs baseline: 1.0856x; 1.0856x over previous
//
#include <hip/hip_runtime.h>

// CRITICAL: bit-exact replication of the numpy fp32 oracle requires NO FMA
// contraction (hipcc default -ffp-contract=fast-honor-pragmas would fuse).
#pragma clang fp contract(off)

#define D4    83521      // 17^4 entries per LUT (per channel)
#define HW    262144     // 512*512
#define NPIX  2097152    // 8*512*512
#define PREC  78608      // 17*17*17*16 pair records per LUT (32 B each)

// ---------- pair32 packing: one 32 B record = cells (i3, i3+1) --------------
// Record r = ((i0*17 + i1)*17 + i2)*16 + i3, i3 in [0,16). 32 B-aligned, so a
// record never straddles a 64 B line -> both corners of the i3 edge are one
// line. Per-LUT size 2.52 MB -> stays resident in the 4 MiB per-XCD L2
// (round 7's 4.7 MB/stage quad broke residency: FETCH 96 MB -> 1.06 GB).
__global__ __launch_bounds__(256) void pack_pair(const float* __restrict__ src,
                                                 int n_ch,
                                                 float4* __restrict__ dst) {
    int e = blockIdx.x * 256 + threadIdx.x;
    if (e >= PREC) return;
    int i3 = e & 15;
    int q  = e >> 4;          // ((i0*17+i1)*17+i2)
    int i2 = q % 17;
    int q2 = q / 17;          // i0*17 + i1
    int i1 = q2 % 17;
    int i0 = q2 / 17;
    int base = i0 * 4913 + i1 * 289 + i2 * 17 + i3;
#pragma unroll
    for (int slot = 0; slot < 2; ++slot) {
        int o = base + slot;
        float4 v;
        v.x = src[o];
        v.y = src[D4 + o];
        v.z = src[2 * D4 + o];
        v.w = (n_ch == 4) ? src[3 * D4 + o] : 0.f;
        dst[(size_t)e * 2 + slot] = v;
    }
}

// Fused 6-stage chain. Per stage: issue ALL 16 gathers into a register array
// (explicit MLP: round 6's VGPR=32 build serialized loads, ~3 in flight ->
// latency-bound), then accumulate in the EXACT round-6 corner order
// (corner c_ref = hi*8 + c, bit k selects dim k) — loads don't affect
// numerics, so bit-exactness is preserved by construction.
__global__ __launch_bounds__(256) void fused_pair(const float* __restrict__ vi,
                                                  const float* __restrict__ ir,
                                                  const float4* __restrict__ luts,
                                                  float* __restrict__ out) {
#pragma clang fp contract(off)
    int p = blockIdx.x * 256 + threadIdx.x;
    if (p >= NPIX) return;
    int b  = p >> 18;             // HW = 2^18
    int hw = p & (HW - 1);
    int vbase = (b * 3) << 18;

    float x0 = vi[vbase + hw];
    float x1 = vi[vbase + HW + hw];
    float x2 = vi[vbase + 2 * HW + hw];
    float x3 = ir[p];

    for (int s = 0; s < 6; ++s) {
        const float4* __restrict__ lut = luts + (size_t)s * PREC * 2;
        x0 = fminf(fmaxf(x0, 0.f), 1.f);
        x1 = fminf(fmaxf(x1, 0.f), 1.f);
        x2 = fminf(fmaxf(x2, 0.f), 1.f);
        x3 = fminf(fmaxf(x3, 0.f), 1.f);

        float xs0 = x0 * 16.f;
        float xs1 = x1 * 16.f;
        float xs2 = x2 * 16.f;
        float xs3 = x3 * 16.f;
        int i0 = (int)xs0; i0 = i0 > 15 ? 15 : i0;
        int i1 = (int)xs1; i1 = i1 > 15 ? 15 : i1;
        int i2 = (int)xs2; i2 = i2 > 15 ? 15 : i2;
        int i3 = (int)xs3; i3 = i3 > 15 ? 15 : i3;
        float f0 = xs0 - (float)i0;   // mul-then-sub, contraction OFF
        float f1 = xs1 - (float)i1;
        float f2 = xs2 - (float)i2;
        float f3 = xs3 - (float)i3;
        float g0 = 1.f - f0;
        float g1 = 1.f - f1;
        float g2 = 1.f - f2;
        float g3 = 1.f - f3;

        // w01[b1*2+b0] = (b0?f0:g0)*(b1?f1:g1)
        float w01[4] = { g0 * g1, f0 * g1, g0 * f1, f0 * f1 };

        // pair record index; record strides: i0->4624, i1->272, i2->16
        int r = ((i0 * 17 + i1) * 17 + i2) * 16 + i3;
        const float4* R = lut + (size_t)r * 2;

        // ---- phase 1: issue all 16 gathers (8 records x 2 slots) ----
        float4 v[16];
#pragma unroll
        for (int c = 0; c < 8; ++c) {
            int d = ((c & 1) * 4624 + ((c >> 1) & 1) * 272 + (c >> 2) * 16) * 2;
            v[c * 2]     = R[d];       // corner c_ref = c      (i3)
            v[c * 2 + 1] = R[d + 1];   // corner c_ref = c + 8  (i3+1)
        }

        // ---- phase 2: exact round-6 sequential accumulation ----
        float a0 = 0.f, a1 = 0.f, a2 = 0.f, a3 = 0.f;
#pragma unroll
        for (int hi = 0; hi < 2; ++hi) {
            float w3 = hi ? f3 : g3;
#pragma unroll
            for (int c = 0; c < 8; ++c) {
                float4 vv = v[c * 2 + hi];
                float w012 = w01[c & 3] * ((c >> 2) ? f2 : g2);
                float w    = w012 * w3;
                if (hi == 0 && c == 0) {
                    a0 = vv.x * w; a1 = vv.y * w; a2 = vv.z * w; a3 = vv.w * w;
                } else {
                    a0 = a0 + vv.x * w; a1 = a1 + vv.y * w;
                    a2 = a2 + vv.z * w; a3 = a3 + vv.w * w;
                }
            }
        }
        x0 = a0; x1 = a1; x2 = a2; x3 = a3;
    }

    out[vbase + hw]          = x0;
    out[vbase + HW + hw]     = x1;
    out[vbase + 2 * HW + hw] = x2;
}

// ---------- middle tier: round-6 linear float4 packing (known-passing) ------
__global__ __launch_bounds__(256) void pack_kernel(const float* __restrict__ src,
                                                   int n_ch,
                                                   float4* __restrict__ dst) {
    int e = blockIdx.x * 256 + threadIdx.x;
    if (e >= D4) return;
    float4 v;
    v.x = src[e];
    v.y = src[D4 + e];
    v.z = src[2 * D4 + e];
    v.w = (n_ch == 4) ? src[3 * D4 + e] : 0.f;
    dst[e] = v;
}

__global__ __launch_bounds__(256) void fused_kernel(const float* __restrict__ vi,
                                                    const float* __restrict__ ir,
                                                    const float4* __restrict__ luts,
                                                    float* __restrict__ out) {
#pragma clang fp contract(off)
    int p = blockIdx.x * 256 + threadIdx.x;
    if (p >= NPIX) return;
    int b  = p >> 18;
    int hw = p & (HW - 1);
    int vbase = (b * 3) << 18;

    float x0 = vi[vbase + hw];
    float x1 = vi[vbase + HW + hw];
    float x2 = vi[vbase + 2 * HW + hw];
    float x3 = ir[p];

    for (int s = 0; s < 6; ++s) {
        const float4* __restrict__ lut = luts + (size_t)s * D4;
        x0 = fminf(fmaxf(x0, 0.f), 1.f);
        x1 = fminf(fmaxf(x1, 0.f), 1.f);
        x2 = fminf(fmaxf(x2, 0.f), 1.f);
        x3 = fminf(fmaxf(x3, 0.f), 1.f);

        float xs0 = x0 * 16.f;
        float xs1 = x1 * 16.f;
        float xs2 = x2 * 16.f;
        float xs3 = x3 * 16.f;
        int i0 = (int)xs0; i0 = i0 > 15 ? 15 : i0;
        int i1 = (int)xs1; i1 = i1 > 15 ? 15 : i1;
        int i2 = (int)xs2; i2 = i2 > 15 ? 15 : i2;
        int i3 = (int)xs3; i3 = i3 > 15 ? 15 : i3;
        float f0 = xs0 - (float)i0;
        float f1 = xs1 - (float)i1;
        float f2 = xs2 - (float)i2;
        float f3 = xs3 - (float)i3;
        float g0 = 1.f - f0;
        float g1 = 1.f - f1;
        float g2 = 1.f - f2;
        float g3 = 1.f - f3;

        float w01[4] = { g0 * g1, f0 * g1, g0 * f1, f0 * f1 };
        int off = i0 * 4913 + i1 * 289 + i2 * 17 + i3;

        float a0 = 0.f, a1 = 0.f, a2 = 0.f, a3 = 0.f;
#pragma unroll
        for (int hi = 0; hi < 2; ++hi) {
            float w3 = hi ? f3 : g3;
#pragma unroll
            for (int c = 0; c < 8; ++c) {
                int d = (c & 1) * 4913 + ((c >> 1) & 1) * 289 + (c >> 2) * 17 + hi;
                float4 v = lut[off + d];
                float w012 = w01[c & 3] * ((c >> 2) ? f2 : g2);
                float w    = w012 * w3;
                if (hi == 0 && c == 0) {
                    a0 = v.x * w; a1 = v.y * w; a2 = v.z * w; a3 = v.w * w;
                } else {
                    a0 = a0 + v.x * w; a1 = a1 + v.y * w;
                    a2 = a2 + v.z * w; a3 = a3 + v.w * w;
                }
            }
        }
        x0 = a0; x1 = a1; x2 = a2; x3 = a3;
    }

    out[vbase + hw]          = x0;
    out[vbase + HW + hw]     = x1;
    out[vbase + 2 * HW + hw] = x2;
}

// ---------- raw fallback (no workspace) -------------------------------------
__global__ __launch_bounds__(256) void fused_fallback(const float* __restrict__ vi,
                                                      const float* __restrict__ ir,
                                                      const float* __restrict__ l8,
                                                      const float* __restrict__ l00,
                                                      const float* __restrict__ l01,
                                                      const float* __restrict__ l02,
                                                      const float* __restrict__ l03,
                                                      const float* __restrict__ lpgf,
                                                      float* __restrict__ out) {
#pragma clang fp contract(off)
    int p = blockIdx.x * 256 + threadIdx.x;
    if (p >= NPIX) return;
    int b  = p >> 18;
    int hw = p & (HW - 1);
    int vbase = (b * 3) << 18;

    const float* ptrs[6] = { l8, l00, l01, l02, l03, lpgf };

    float x0 = vi[vbase + hw];
    float x1 = vi[vbase + HW + hw];
    float x2 = vi[vbase + 2 * HW + hw];
    float x3 = ir[p];

    for (int s = 0; s < 6; ++s) {
        const float* __restrict__ L = ptrs[s];
        int n_ch = (s == 5) ? 3 : 4;
        x0 = fminf(fmaxf(x0, 0.f), 1.f);
        x1 = fminf(fmaxf(x1, 0.f), 1.f);
        x2 = fminf(fmaxf(x2, 0.f), 1.f);
        x3 = fminf(fmaxf(x3, 0.f), 1.f);
        float xs0 = x0 * 16.f;
        float xs1 = x1 * 16.f;
        float xs2 = x2 * 16.f;
        float xs3 = x3 * 16.f;
        int i0 = (int)xs0; i0 = i0 > 15 ? 15 : i0;
        int i1 = (int)xs1; i1 = i1 > 15 ? 15 : i1;
        int i2 = (int)xs2; i2 = i2 > 15 ? 15 : i2;
        int i3 = (int)xs3; i3 = i3 > 15 ? 15 : i3;
        float f0 = xs0 - (float)i0;
        float f1 = xs1 - (float)i1;
        float f2 = xs2 - (float)i2;
        float f3 = xs3 - (float)i3;
        float g0 = 1.f - f0;
        float g1 = 1.f - f1;
        float g2 = 1.f - f2;
        float g3 = 1.f - f3;
        float w01[4] = { g0 * g1, f0 * g1, g0 * f1, f0 * f1 };
        int off = i0 * 4913 + i1 * 289 + i2 * 17 + i3;
        float a0 = 0.f, a1 = 0.f, a2 = 0.f, a3 = 0.f;
        for (int cr = 0; cr < 16; ++cr) {
            int hi = cr >> 3, c = cr & 7;
            int idx = off + (c & 1) * 4913 + ((c >> 1) & 1) * 289 + (c >> 2) * 17 + hi;
            float w012 = w01[c & 3] * ((c >> 2) ? f2 : g2);
            float w    = w012 * (hi ? f3 : g3);
            float v0 = L[idx];
            float v1 = L[D4 + idx];
            float v2 = L[2 * D4 + idx];
            float v3 = (n_ch == 4) ? L[3 * D4 + idx] : 0.f;
            if (cr == 0) {
                a0 = v0 * w; a1 = v1 * w; a2 = v2 * w; a3 = v3 * w;
            } else {
                a0 = a0 + v0 * w; a1 = a1 + v1 * w;
                a2 = a2 + v2 * w; a3 = a3 + v3 * w;
            }
        }
        x0 = a0; x1 = a1; x2 = a2; x3 = a3;
    }

    out[vbase + hw]          = x0;
    out[vbase + HW + hw]     = x1;
    out[vbase + 2 * HW + hw] = x2;
}

extern "C" void kernel_launch(void* const* d_in, const int* in_sizes, int n_in,
                              void* d_out, int out_size, void* d_ws, size_t ws_size,
                              hipStream_t stream) {
    const float* vi = (const float*)d_in[0];
    const float* ir = (const float*)d_in[1];
    const float* raw[6] = {
        (const float*)d_in[2], (const float*)d_in[3],
        (const float*)d_in[4], (const float*)d_in[5],
        (const float*)d_in[6], (const float*)d_in[7]
    };
    float* out = (float*)d_out;

    size_t need_pair = (size_t)6 * PREC * 32;            // ~15.1 MB
    size_t need_lin  = (size_t)6 * D4 * sizeof(float4);  // ~8.0 MB

    if (ws_size >= need_pair) {
        float4* packed = (float4*)d_ws;
        int pack_blocks = (PREC + 255) / 256;
        for (int s = 0; s < 6; ++s) {
            pack_pair<<<pack_blocks, 256, 0, stream>>>(raw[s], (s == 5) ? 3 : 4,
                                                       packed + (size_t)s * PREC * 2);
        }
        fused_pair<<<NPIX / 256, 256, 0, stream>>>(vi, ir, packed, out);
    } else if (ws_size >= need_lin) {
        float4* packed = (float4*)d_ws;
        int pack_blocks = (D4 + 255) / 256;
        for (int s = 0; s < 6; ++s) {
            pack_kernel<<<pack_blocks, 256, 0, stream>>>(raw[s], (s == 5) ? 3 : 4,
                                                         packed + (size_t)s * D4);
        }
        fused_kernel<<<NPIX / 256, 256, 0, stream>>>(vi, ir, packed, out);
    } else {
        fused_fallback<<<NPIX / 256, 256, 0, stream>>>(vi, ir, raw[0], raw[1], raw[2],
                                                       raw[3], raw[4], raw[5], out);
    }
}